// Round 5
// baseline (585.943 us; speedup 1.0000x reference)
//
#include <hip/hip_runtime.h>
#include <hip/hip_cooperative_groups.h>

namespace cg = cooperative_groups;

#define SCALE 0.0625f  // C^-0.5 = 1/16
#define ROW 36         // dwords per o-row in conv LDS slab (32 px + 4 pad)

typedef __attribute__((ext_vector_type(4))) float f32x4;
typedef __attribute__((ext_vector_type(8))) short s16x8;
typedef __attribute__((ext_vector_type(8))) unsigned short u16x8;

__device__ __forceinline__ unsigned short f2bf(float x) {
    unsigned u = __float_as_uint(x);
    u = u + 0x7FFF + ((u >> 16) & 1);   // RNE; inputs finite
    return (unsigned short)(u >> 16);
}

// ---------------------------------------------------------------------------
// prep1: blocks 0..15  -> q[b,c] = TO[b] . Wq[c] + bq[c]
//        blocks 16..31 -> WvB = bf16(Wv)   (row-major [co][o], no transpose)
// ---------------------------------------------------------------------------
__global__ __launch_bounds__(256) void prep1_kernel(
    const float* __restrict__ TO,    // [2,1024]
    const float* __restrict__ Wq,    // [256,1024]
    const float* __restrict__ bq,    // [256]
    const float* __restrict__ Wv,    // [256,256]
    float* __restrict__ qbuf,        // [2,256]
    unsigned short* __restrict__ WvB)// [256,256] bf16
{
    const int blk = blockIdx.x;
    const int t   = threadIdx.x;
    if (blk < 16) {
        const int b    = blk >> 3;
        const int rblk = blk & 7;
        const int wv = t >> 6, l = t & 63;
        const float4* Wq4 = (const float4*)Wq;
        const float4* TO4 = (const float4*)TO;
        for (int rr = 0; rr < 8; ++rr) {
            const int c = rblk * 32 + wv * 8 + rr;
            float acc = 0.f;
#pragma unroll
            for (int i = 0; i < 4; ++i) {
                float4 wq = Wq4[c * 256 + i * 64 + l];
                float4 tv = TO4[b * 256 + i * 64 + l];
                acc = fmaf(wq.x, tv.x, acc);
                acc = fmaf(wq.y, tv.y, acc);
                acc = fmaf(wq.z, tv.z, acc);
                acc = fmaf(wq.w, tv.w, acc);
            }
#pragma unroll
            for (int mask = 1; mask < 64; mask <<= 1)
                acc += __shfl_xor(acc, mask, 64);
            if (l == 0) qbuf[b * 256 + c] = acc + bq[c];
        }
    } else {
        const int idx = blk - 16;   // 0..15, 4096 elements each
#pragma unroll
        for (int i = 0; i < 4; ++i) {
            const int e = idx * 4096 + i * 1024 + t * 4;
            const float4 f = ((const float4*)Wv)[e >> 2];
            ushort4 o;
            o.x = f2bf(f.x); o.y = f2bf(f.y);
            o.z = f2bf(f.z); o.w = f2bf(f.w);
            *(ushort4*)(WvB + e) = o;
        }
    }
}

// ---------------------------------------------------------------------------
// fused cooperative kernel: 256 blocks x 512 thr, 1 block/CU co-resident.
// Phases separated by grid.sync() (no inter-kernel launch gaps):
//   0: prep2  (blocks 0..15)  qks = SCALE * q . Wk
//   A: score  (all)           Sp[ch][b][m][px] partial dots, contiguous 512KB/blk
//   B: softmax(blocks 0..31)  P[b][m][px] (in-wave shfl reduce over m; each
//                             thread covers TWO float4 columns -> full 4096 px)
//   C: wsum   (all)           Ybf[b][o][px] = bf16(sum_m P * X)  -- X re-read
//                             should be L3-resident from phase A (134MB < 256MB)
//   D: conv   (all)           out = Wv.Y + bv via bf16 MFMA (r3 epilogue)
// ---------------------------------------------------------------------------
__global__ __launch_bounds__(512, 2) void fused_kernel(
    const float* __restrict__ X,     // [2,16,256,4096]
    const float* __restrict__ qbuf,  // [2,256]
    const float* __restrict__ Wk,    // [256,256]
    float* __restrict__ qks,         // [2,256]
    float* __restrict__ Sp,          // [8][2][16][4096]
    float* __restrict__ P,           // [2][16][4096]
    unsigned short* __restrict__ Ybf,// [2][256][4096] bf16
    const unsigned short* __restrict__ WvB,  // [256,256] bf16
    const float* __restrict__ bv,    // [256]
    float* __restrict__ out)         // [2,256,4096]
{
    cg::grid_group grid = cg::this_grid();
    const int blk = blockIdx.x;      // 0..255
    const int t   = threadIdx.x;     // 0..511

    __shared__ float slab[256 * ROW];   // conv slab (36 KB)
    __shared__ float r2[16][32];        // prep2 scratch

    // ---- phase 0: prep2 on blocks 0..15 ---------------------------------
    if (blk < 16) {
        const int b = blk >> 3, j = blk & 7;
        const int col = t & 31, chunk = t >> 5;   // chunk 0..15
        const int cp = j * 32 + col;
        float partial = 0.f;
#pragma unroll
        for (int cc = 0; cc < 16; ++cc) {
            const int c = chunk * 16 + cc;
            partial = fmaf(qbuf[b * 256 + c], Wk[c * 256 + cp], partial);
        }
        r2[chunk][col] = partial;
        __syncthreads();
        if (t < 32) {
            float s = 0.f;
#pragma unroll
            for (int k = 0; k < 16; ++k) s += r2[k][t];
            qks[b * 256 + j * 32 + t] = SCALE * s;
        }
    }
    __threadfence();
    grid.sync();

    // ---- phase A: score (contiguous streaming) --------------------------
    {
        const int ch = blk & 7;
        const int bm = blk >> 3;         // b*16+m
        const int b  = bm >> 4;
        const int c0 = ch * 32;
        const float4* X4 = (const float4*)X;
        const int base = (bm * 256 + c0) * 1024;   // float4 units

        float4 a0 = make_float4(0.f, 0.f, 0.f, 0.f);
        float4 a1 = make_float4(0.f, 0.f, 0.f, 0.f);
#pragma unroll 4
        for (int c = 0; c < 32; ++c) {
            const float q = qks[b * 256 + c0 + c];
            const float4 x0 = X4[base + c * 1024 + t];
            const float4 x1 = X4[base + c * 1024 + t + 512];
            a0.x = fmaf(q, x0.x, a0.x); a0.y = fmaf(q, x0.y, a0.y);
            a0.z = fmaf(q, x0.z, a0.z); a0.w = fmaf(q, x0.w, a0.w);
            a1.x = fmaf(q, x1.x, a1.x); a1.y = fmaf(q, x1.y, a1.y);
            a1.z = fmaf(q, x1.z, a1.z); a1.w = fmaf(q, x1.w, a1.w);
        }
        float4* S4 = (float4*)(Sp + (ch * 32 + bm) * 4096);
        S4[t]       = a0;
        S4[t + 512] = a1;
    }
    __threadfence();
    grid.sync();

    // ---- phase B: softmax over m, blocks 0..31 --------------------------
    if (blk < 32) {
        const int b = blk >> 4, g = blk & 15;
        const int m = t & 15, f4g = t >> 4;       // f4g 0..31
        const float4* Sp4 = (const float4*)Sp;
#pragma unroll
        for (int rep = 0; rep < 2; ++rep) {
            const int f4c = g * 64 + rep * 32 + f4g;   // 0..1023: full coverage
            float4 s = make_float4(0.f, 0.f, 0.f, 0.f);
#pragma unroll
            for (int ch = 0; ch < 8; ++ch) {
                const float4 v = Sp4[((ch * 2 + b) * 16 + m) * 1024 + f4c];
                s.x += v.x; s.y += v.y; s.z += v.z; s.w += v.w;
            }
            float4 e;
            e.x = __expf(s.x); e.y = __expf(s.y);
            e.z = __expf(s.z); e.w = __expf(s.w);
            float4 tot = e;
#pragma unroll
            for (int mask = 1; mask < 16; mask <<= 1) {  // reduce over 16 m-lanes
                tot.x += __shfl_xor(tot.x, mask, 64);
                tot.y += __shfl_xor(tot.y, mask, 64);
                tot.z += __shfl_xor(tot.z, mask, 64);
                tot.w += __shfl_xor(tot.w, mask, 64);
            }
            float4 p;
            p.x = e.x / tot.x; p.y = e.y / tot.y;
            p.z = e.z / tot.z; p.w = e.w / tot.w;
            ((float4*)P)[(b * 16 + m) * 1024 + f4c] = p;
        }
    }
    __threadfence();
    grid.sync();

    // ---- phase C: wsum (X re-read; expected L3-resident) ----------------
    {
        const int ph = blk & 1;
        const int oc = (blk >> 1) & 63;
        const int b  = blk >> 7;
        const int o0 = oc * 4;
        const int px4 = (ph << 9) + t;   // float4 index in the 1024-f4 row
        const float4* X4 = (const float4*)X;
        const float4* P4 = (const float4*)P;

        float4 acc[4];
#pragma unroll
        for (int o = 0; o < 4; ++o) acc[o] = make_float4(0.f, 0.f, 0.f, 0.f);

#pragma unroll 2
        for (int m = 0; m < 16; ++m) {
            const float4 p = P4[(b * 16 + m) * 1024 + px4];
#pragma unroll
            for (int o = 0; o < 4; ++o) {
                const float4 x = X4[((b * 16 + m) * 256 + o0 + o) * 1024 + px4];
                acc[o].x = fmaf(p.x, x.x, acc[o].x);
                acc[o].y = fmaf(p.y, x.y, acc[o].y);
                acc[o].z = fmaf(p.z, x.z, acc[o].z);
                acc[o].w = fmaf(p.w, x.w, acc[o].w);
            }
        }
#pragma unroll
        for (int o = 0; o < 4; ++o) {
            ushort4 y;
            y.x = f2bf(acc[o].x); y.y = f2bf(acc[o].y);
            y.z = f2bf(acc[o].z); y.w = f2bf(acc[o].w);
            *(ushort4*)(Ybf + (b * 256 + o0 + o) * 4096 + px4 * 4) = y;
        }
    }
    __threadfence();
    grid.sync();

    // ---- phase D: conv (bf16 MFMA epilogue) -----------------------------
    {
        const int b   = blk >> 7;
        const int px0 = (blk & 127) << 5;
        const int lane = t & 63;
        const int w    = t >> 6;

        {   // stage Y-tile: thread t -> rows o = t>>2 (+128), quarter q = t&3
            const int o = t >> 2, q = t & 3;
#pragma unroll
            for (int h = 0; h < 2; ++h) {
                const int oo = o + h * 128;
                const u16x8 v = *(const u16x8*)(Ybf + (b * 256 + oo) * 4096 + px0 + q * 8);
#pragma unroll
                for (int j = 0; j < 8; ++j)
                    slab[oo * ROW + q * 8 + j] =
                        __uint_as_float((unsigned)(unsigned short)v[j] << 16);
            }
        }
        __syncthreads();

        const int px16 = lane & 15;
        const int quad = lane >> 4;

        f32x4 acc[2][2];   // [tl][pxh]
#pragma unroll
        for (int tl = 0; tl < 2; ++tl)
#pragma unroll
            for (int pxh = 0; pxh < 2; ++pxh)
#pragma unroll
                for (int r = 0; r < 4; ++r)
                    acc[tl][pxh][r] = bv[16 * (w * 2 + tl) + quad * 4 + r];

#pragma unroll
        for (int ks = 0; ks < 8; ++ks) {   // K = 256 in steps of 32
            s16x8 bfr[2];
#pragma unroll
            for (int pxh = 0; pxh < 2; ++pxh)
#pragma unroll
                for (int j = 0; j < 8; ++j)
                    bfr[pxh][j] = (short)f2bf(
                        slab[(ks * 32 + quad * 8 + j) * ROW + pxh * 16 + px16]);
#pragma unroll
            for (int tl = 0; tl < 2; ++tl) {
                const s16x8 afr = *(const s16x8*)(
                    WvB + (16 * (w * 2 + tl) + px16) * 256 + ks * 32 + quad * 8);
#pragma unroll
                for (int pxh = 0; pxh < 2; ++pxh)
                    acc[tl][pxh] = __builtin_amdgcn_mfma_f32_16x16x32_bf16(
                        afr, bfr[pxh], acc[tl][pxh], 0, 0, 0);
            }
        }

        const int obase = b * 256 * 4096 + px0;
#pragma unroll
        for (int tl = 0; tl < 2; ++tl)
#pragma unroll
            for (int pxh = 0; pxh < 2; ++pxh)
#pragma unroll
                for (int r = 0; r < 4; ++r) {
                    const int co = 16 * (w * 2 + tl) + quad * 4 + r;
                    out[obase + co * 4096 + pxh * 16 + px16] = acc[tl][pxh][r];
                }
    }
}

// ---------------------------------------------------------------------------
extern "C" void kernel_launch(void* const* d_in, const int* in_sizes, int n_in,
                              void* d_out, int out_size, void* d_ws, size_t ws_size,
                              hipStream_t stream) {
    const float* TO = (const float*)d_in[0];   // [2,1024]
    const float* X  = (const float*)d_in[1];   // [2,16,256,64,64]
    const float* Wq = (const float*)d_in[2];   // [256,1024]
    const float* bq = (const float*)d_in[3];   // [256]
    const float* Wk = (const float*)d_in[4];   // [256,256]
    // d_in[5] = bk: dropped (softmax-invariant)
    const float* Wv = (const float*)d_in[6];   // [256,256]
    const float* bv = (const float*)d_in[7];   // [256]
    float* out = (float*)d_out;
    float* ws  = (float*)d_ws;

    // workspace carve (float units):
    float*          qbuf = ws;                         // 512
    float*          qks  = ws + 512;                   // 512
    unsigned short* WvB  = (unsigned short*)(ws + 1024);          // 65536 u16
    float*          Sp   = ws + 33792;                 // 8*2*16*4096 = 1048576
    float*          P    = ws + 1082368;               // 2*16*4096  = 131072
    unsigned short* Ybf  = (unsigned short*)(ws + 1213440);       // 2*256*4096 u16

    hipLaunchKernelGGL(prep1_kernel, dim3(32), dim3(256), 0, stream,
                       TO, Wq, bq, Wv, qbuf, WvB);

    void* args[] = {(void*)&X, (void*)&qbuf, (void*)&Wk, (void*)&qks,
                    (void*)&Sp, (void*)&P, (void*)&Ybf, (void*)&WvB,
                    (void*)&bv, (void*)&out};
    hipLaunchCooperativeKernel((const void*)fused_kernel, dim3(256), dim3(512),
                               args, 0, stream);
}

// Round 7
// 323.642 us; speedup vs baseline: 1.8105x; 1.8105x over previous
//
#include <hip/hip_runtime.h>

#define SCALE 0.0625f  // C^-0.5 = 1/16
#define ROW 36         // dwords per o-row in conv LDS slab (32 px + 4 pad)

typedef __attribute__((ext_vector_type(4))) float f32x4;
typedef __attribute__((ext_vector_type(8))) short s16x8;
typedef __attribute__((ext_vector_type(8))) unsigned short u16x8;

__device__ __forceinline__ unsigned short f2bf(float x) {
    unsigned u = __float_as_uint(x);
    u = u + 0x7FFF + ((u >> 16) & 1);   // RNE; inputs finite
    return (unsigned short)(u >> 16);
}

// ---------------------------------------------------------------------------
// prep: blocks 0..1  -> q[b,:] (LDS) then qks[b,:] = SCALE * q . Wk  (fused
//                      prep1+prep2: saves a dispatch + its gap)
//       blocks 2..17 -> WvB = bf16(Wv)  (row-major [co][o])
// ---------------------------------------------------------------------------
__global__ __launch_bounds__(256) void prep_kernel(
    const float* __restrict__ TO,    // [2,1024]
    const float* __restrict__ Wq,    // [256,1024]
    const float* __restrict__ bq,    // [256]
    const float* __restrict__ Wk,    // [256,256]
    const float* __restrict__ Wv,    // [256,256]
    float* __restrict__ qks,         // [2,256] (pre-scaled)
    unsigned short* __restrict__ WvB)// [256,256] bf16
{
    const int blk = blockIdx.x;
    const int t   = threadIdx.x;
    if (blk < 2) {
        const int b = blk;
        __shared__ float sq[256];
        const int wv = t >> 6, l = t & 63;
        const float4* Wq4 = (const float4*)Wq;
        const float4* TO4 = (const float4*)TO;
        // phase 1: q[b,c] = TO[b].Wq[c] + bq[c]; wave wv owns rows wv*64..+63
        for (int rr = 0; rr < 64; ++rr) {
            const int c = wv * 64 + rr;
            float acc = 0.f;
#pragma unroll
            for (int i = 0; i < 4; ++i) {
                float4 wq = Wq4[c * 256 + i * 64 + l];
                float4 tv = TO4[b * 256 + i * 64 + l];
                acc = fmaf(wq.x, tv.x, acc);
                acc = fmaf(wq.y, tv.y, acc);
                acc = fmaf(wq.z, tv.z, acc);
                acc = fmaf(wq.w, tv.w, acc);
            }
#pragma unroll
            for (int mask = 1; mask < 64; mask <<= 1)
                acc += __shfl_xor(acc, mask, 64);
            if (l == 0) sq[c] = acc + bq[c];
        }
        __syncthreads();
        // phase 2: qks[b,cp] = SCALE * sum_c sq[c] * Wk[c][cp]
        float val = 0.f;
#pragma unroll 8
        for (int c = 0; c < 256; ++c)
            val = fmaf(sq[c], Wk[c * 256 + t], val);
        qks[b * 256 + t] = SCALE * val;
    } else {
        const int idx = blk - 2;   // 0..15, 4096 elements each
#pragma unroll
        for (int i = 0; i < 4; ++i) {
            const int e = idx * 4096 + i * 1024 + t * 4;
            const float4 f = ((const float4*)Wv)[e >> 2];
            ushort4 o;
            o.x = f2bf(f.x); o.y = f2bf(f.y);
            o.z = f2bf(f.z); o.w = f2bf(f.w);
            *(ushort4*)(WvB + e) = o;
        }
    }
}

// ---------------------------------------------------------------------------
// score: FULL dot products (no c-chunk partials -> no Sp reduce pass).
//   512 blocks = bm(32) x pxq(16), 256 thr, 2 blocks/CU (16 waves/CU).
//   Thread (cg = t>>6, f4l = t&63): partial over its 64 c's for f4-col
//   pxq*64+f4l; each wave-load = 64 consecutive float4 = 1KB contiguous
//   span per (m,c) row (DRAM-page friendly). LDS reduce over the 4 cg.
//   S[b][m][px] = full score (0.5 MB total).
// ---------------------------------------------------------------------------
__global__ __launch_bounds__(256, 2) void score_kernel(
    const float* __restrict__ X,     // [2,16,256,4096]
    const float* __restrict__ qks,   // [2,256] (pre-scaled)
    float* __restrict__ S)           // [2][16][4096]
{
    const int blk = blockIdx.x;      // bm*16 + pxq
    const int bm  = blk >> 4;        // b*16+m
    const int pxq = blk & 15;
    const int b   = bm >> 4;
    const int t   = threadIdx.x;
    const int cg  = t >> 6, f4l = t & 63;

    const float4* X4 = (const float4*)X;
    const int base = (bm * 256 + cg * 64) * 1024 + pxq * 64 + f4l;
    const float* q = qks + b * 256 + cg * 64;

    float4 a = make_float4(0.f, 0.f, 0.f, 0.f);
#pragma unroll 8
    for (int cc = 0; cc < 64; ++cc) {
        const float4 x = X4[base + cc * 1024];
        const float qv = q[cc];
        a.x = fmaf(qv, x.x, a.x);
        a.y = fmaf(qv, x.y, a.y);
        a.z = fmaf(qv, x.z, a.z);
        a.w = fmaf(qv, x.w, a.w);
    }
    __shared__ float4 part[4][64];
    part[cg][f4l] = a;
    __syncthreads();
    if (t < 64) {
        const float4 s0 = part[0][t], s1 = part[1][t];
        const float4 s2 = part[2][t], s3 = part[3][t];
        float4 r;
        r.x = s0.x + s1.x + s2.x + s3.x;
        r.y = s0.y + s1.y + s2.y + s3.y;
        r.z = s0.z + s1.z + s2.z + s3.z;
        r.w = s0.w + s1.w + s2.w + s3.w;
        ((float4*)S)[bm * 1024 + pxq * 64 + t] = r;
    }
}

// ---------------------------------------------------------------------------
// wsum (+ in-register softmax): Ybf[b,o,px] = bf16(sum_m P * X).
//   512 blocks = b(2) x oc(64) x pxq(4), 256 thr, 2 blocks/CU.
//   Thread owns one f4-col: loads 16 S values, softmax in regs (max-free),
//   then streams X[b,m,o0..o0+3, px-range] (4-KB spans; X is L3-resident
//   from the score pass -> FETCH for this kernel should be small).
// ---------------------------------------------------------------------------
__global__ __launch_bounds__(256, 2) void wsum_kernel(
    const float* __restrict__ X,     // [2,16,256,4096]
    const float* __restrict__ S,     // [2][16][4096]
    unsigned short* __restrict__ Ybf)// [2][256][4096] bf16
{
    const int blk = blockIdx.x;      // ((b*64+oc)<<2) | pxq
    const int pxq = blk & 3;
    const int oc  = (blk >> 2) & 63;
    const int b   = blk >> 8;
    const int t   = threadIdx.x;
    const int px4 = pxq * 256 + t;   // f4 col 0..1023
    const int o0  = oc * 4;
    const float4* X4 = (const float4*)X;
    const float4* S4 = (const float4*)S;

    // softmax over m, entirely in registers
    float4 p[16];
    float4 tot = make_float4(0.f, 0.f, 0.f, 0.f);
#pragma unroll
    for (int m = 0; m < 16; ++m) {
        const float4 s = S4[(b * 16 + m) * 1024 + px4];
        p[m].x = __expf(s.x); p[m].y = __expf(s.y);
        p[m].z = __expf(s.z); p[m].w = __expf(s.w);
        tot.x += p[m].x; tot.y += p[m].y;
        tot.z += p[m].z; tot.w += p[m].w;
    }
    const float ix = 1.0f / tot.x, iy = 1.0f / tot.y;
    const float iz = 1.0f / tot.z, iw = 1.0f / tot.w;
#pragma unroll
    for (int m = 0; m < 16; ++m) {
        p[m].x *= ix; p[m].y *= iy; p[m].z *= iz; p[m].w *= iw;
    }

    float4 acc[4];
#pragma unroll
    for (int o = 0; o < 4; ++o) acc[o] = make_float4(0.f, 0.f, 0.f, 0.f);

#pragma unroll 2
    for (int m = 0; m < 16; ++m) {
        const float4 pm = p[m];
#pragma unroll
        for (int o = 0; o < 4; ++o) {
            const float4 x = X4[((b * 16 + m) * 256 + o0 + o) * 1024 + px4];
            acc[o].x = fmaf(pm.x, x.x, acc[o].x);
            acc[o].y = fmaf(pm.y, x.y, acc[o].y);
            acc[o].z = fmaf(pm.z, x.z, acc[o].z);
            acc[o].w = fmaf(pm.w, x.w, acc[o].w);
        }
    }
#pragma unroll
    for (int o = 0; o < 4; ++o) {
        ushort4 y;
        y.x = f2bf(acc[o].x); y.y = f2bf(acc[o].y);
        y.z = f2bf(acc[o].z); y.w = f2bf(acc[o].w);
        *(ushort4*)(Ybf + (b * 256 + o0 + o) * 4096 + px4 * 4) = y;
    }
}

// ---------------------------------------------------------------------------
// conv: out[b,co,px] = bv[co] + sum_o Wv[co,o] * Y[b,o,px] via bf16 MFMA.
//    256 blocks = (b, 32-px tile), 512 thr (8 waves). r3's proven kernel.
// ---------------------------------------------------------------------------
__global__ __launch_bounds__(512) void conv_kernel(
    const unsigned short* __restrict__ Ybf,  // [2][256][4096] bf16
    const unsigned short* __restrict__ WvB,  // [256,256] bf16, row-major co x o
    const float* __restrict__ bv,    // [256]
    float* __restrict__ out)         // [2,256,4096]
{
    const int blk = blockIdx.x;      // b*128 + tile
    const int b   = blk >> 7;
    const int px0 = (blk & 127) << 5;
    const int t   = threadIdx.x;
    const int lane = t & 63;
    const int w    = t >> 6;

    __shared__ float slab[256 * ROW];

    {   // stage: thread t -> rows o = t>>2 (+128), quarter q = t&3 (8 px)
        const int o = t >> 2, q = t & 3;
#pragma unroll
        for (int h = 0; h < 2; ++h) {
            const int oo = o + h * 128;
            const u16x8 v = *(const u16x8*)(Ybf + (b * 256 + oo) * 4096 + px0 + q * 8);
#pragma unroll
            for (int j = 0; j < 8; ++j)
                slab[oo * ROW + q * 8 + j] =
                    __uint_as_float((unsigned)(unsigned short)v[j] << 16);
        }
    }
    __syncthreads();

    const int px16 = lane & 15;
    const int quad = lane >> 4;

    f32x4 acc[2][2];   // [tl][pxh]
#pragma unroll
    for (int tl = 0; tl < 2; ++tl)
#pragma unroll
        for (int pxh = 0; pxh < 2; ++pxh)
#pragma unroll
            for (int r = 0; r < 4; ++r)
                acc[tl][pxh][r] = bv[16 * (w * 2 + tl) + quad * 4 + r];

#pragma unroll
    for (int ks = 0; ks < 8; ++ks) {   // K = 256 in steps of 32
        s16x8 bfr[2];
#pragma unroll
        for (int pxh = 0; pxh < 2; ++pxh)
#pragma unroll
            for (int j = 0; j < 8; ++j)
                bfr[pxh][j] = (short)f2bf(
                    slab[(ks * 32 + quad * 8 + j) * ROW + pxh * 16 + px16]);
#pragma unroll
        for (int tl = 0; tl < 2; ++tl) {
            const s16x8 afr = *(const s16x8*)(
                WvB + (16 * (w * 2 + tl) + px16) * 256 + ks * 32 + quad * 8);
#pragma unroll
            for (int pxh = 0; pxh < 2; ++pxh)
                acc[tl][pxh] = __builtin_amdgcn_mfma_f32_16x16x32_bf16(
                    afr, bfr[pxh], acc[tl][pxh], 0, 0, 0);
        }
    }

    const int obase = b * 256 * 4096 + px0;
#pragma unroll
    for (int tl = 0; tl < 2; ++tl)
#pragma unroll
        for (int pxh = 0; pxh < 2; ++pxh)
#pragma unroll
            for (int r = 0; r < 4; ++r) {
                const int co = 16 * (w * 2 + tl) + quad * 4 + r;
                out[obase + co * 4096 + pxh * 16 + px16] = acc[tl][pxh][r];
            }
}

// ---------------------------------------------------------------------------
extern "C" void kernel_launch(void* const* d_in, const int* in_sizes, int n_in,
                              void* d_out, int out_size, void* d_ws, size_t ws_size,
                              hipStream_t stream) {
    const float* TO = (const float*)d_in[0];   // [2,1024]
    const float* X  = (const float*)d_in[1];   // [2,16,256,64,64]
    const float* Wq = (const float*)d_in[2];   // [256,1024]
    const float* bq = (const float*)d_in[3];   // [256]
    const float* Wk = (const float*)d_in[4];   // [256,256]
    // d_in[5] = bk: dropped (softmax-invariant)
    const float* Wv = (const float*)d_in[6];   // [256,256]
    const float* bv = (const float*)d_in[7];   // [256]
    float* out = (float*)d_out;
    float* ws  = (float*)d_ws;

    // workspace carve (float units):
    float*          qks = ws;                          // 512
    unsigned short* WvB = (unsigned short*)(ws + 512);           // 65536 u16
    float*          S   = ws + 33280;                  // 2*16*4096 = 131072
    unsigned short* Ybf = (unsigned short*)(ws + 164352);        // 2*256*4096 u16

    hipLaunchKernelGGL(prep_kernel, dim3(18), dim3(256), 0, stream,
                       TO, Wq, bq, Wk, Wv, qks, WvB);
    hipLaunchKernelGGL(score_kernel, dim3(512), dim3(256), 0, stream,
                       X, qks, S);
    hipLaunchKernelGGL(wsum_kernel, dim3(512), dim3(256), 0, stream,
                       X, S, Ybf);
    hipLaunchKernelGGL(conv_kernel, dim3(256), dim3(512), 0, stream,
                       Ybf, WvB, bv, out);
}